// Round 9
// baseline (486.539 us; speedup 1.0000x reference)
//
#include <hip/hip_runtime.h>

typedef float v2f __attribute__((ext_vector_type(2)));
typedef float v4f __attribute__((ext_vector_type(4)));

#define B_ 64
#define N_ 4096
#define C_ 128
#define W_ 64
#define WIN_ 4033
#define CG 16       // channels per block
#define NCHUNK 64   // n per staged chunk (halved vs r8 -> 16.6 KB LDS, residency test)
#define NSPLIT 4    // grid-level split of the n range (2048 blocks = 8/CU of work)
#define KPAD 4176   // padded w row: kk = k + 64, k in [-64, 4112)
#define WROW 128    // staged u range per chunk (NCHUNK + 64); pow2 -> shift indexing
#define WSTRIDE 129 // LDS w row stride in float2 -- ODD so cl rows land on distinct bank pairs

// Build interleaved, zero-padded weight table w2pad[c][kk] = (wr[c][k], wi[c][k]), k = kk-64
__global__ void prep_w(const float* __restrict__ wr, const float* __restrict__ wi,
                       v2f* __restrict__ w2pad) {
  int idx = blockIdx.x * 256 + threadIdx.x;  // exact: C_*KPAD = 2088*256
  int c = idx / KPAD;
  int kk = idx - c * KPAD;
  int k = kk - 64;
  v2f v = {0.f, 0.f};
  if (k >= 0 && k < WIN_) {
    v.x = wr[c * WIN_ + k];
    v.y = wi[c * WIN_ + k];
  }
  w2pad[idx] = v;
}

// Zero the fq accumulator (B*64*C v2f = 4.19 MB). 1024 blocks x 256 threads x 1 v4f.
__global__ void zero_fq(v4f* __restrict__ fqv) {
  fqv[(size_t)blockIdx.x * 256 + threadIdx.x] = (v4f){0.f, 0.f, 0.f, 0.f};
}

// Depthwise sliding correlation (both components packed), pre-nonlinearity partials.
// Grid: 64 b * 8 cgroups * NSPLIT = 2048 blocks, 256 threads, 16.6 KB LDS.
// Residency experiment (r8 post-mortem): resident blocks/CU tracked ~(100KB / LDS size)
// across all rounds (49.7KB->2, 25KB->3.1); halving LDS to 16.6KB should yield ~6
// resident blocks = 6 waves/SIMD, saturating the VALU at the measured ~15% per-wave duty.
// launch_bounds(256,3): cap 170 -> this body compiles to 64 VGPR, zero scratch (r2/r5/r8).
// Thread roles: cl = tid&15 (channel), t0g = (tid>>4)&3 (t-block), np = tid>>6 (16 n each).
__global__ __launch_bounds__(256, 3) void conv_main(
    const v2f* __restrict__ x2,     // [B][N][C] float2 (r,i)
    const v2f* __restrict__ w2pad,  // [C][KPAD]
    v2f* __restrict__ fq) {         // [B][64 t][C] accumulated via atomicAdd across ns
  __shared__ __attribute__((aligned(16))) v2f wsh[2080];  // max(16*129=2064 stage, 2080 epi) = 16.6 KB

  int tid = threadIdx.x;
  int bid = blockIdx.x;
  int cg = bid & 7;  // XCD-friendly: each XCD sees one w-slice (L2-resident, 535 KB)
  int bb = (bid >> 3) & 63;
  int ns = bid >> 9;
  int cbase = cg * CG;
  int cl = tid & 15;
  int t0 = ((tid >> 4) & 3) << 4;
  int np = tid >> 6;
  int nbase = np << 4;  // 16 n per wave-partition

  v2f zero = {0.f, 0.f};
  v2f acc[16];
#pragma unroll
  for (int i = 0; i < 16; i++) acc[i] = zero;

  const v2f* xg = x2 + (size_t)bb * N_ * C_ + cbase + cl;
  const v2f* wrow = wsh + cl * WSTRIDE;

  int nstart = ns * (N_ / NSPLIT);
  int nend = nstart + N_ / NSPLIT;  // 1024-n range -> 16 chunks of 64

  // invariant: wold[m] = w2loc[nb+64-t0-16+m]; loads wnew[j] = w2loc[nb+64-t0+j]
  auto do16 = [&](int nb, const v2f* xv, const v2f* wold, v2f* wnew) {
#pragma unroll
    for (int j = 0; j < 16; j++) wnew[j] = wrow[nb + 64 - t0 + j];
#pragma unroll
    for (int j = 0; j < 16; j++) {
#pragma unroll
      for (int i = 0; i < 16; i++) {
        int e = j - i;  // need w2loc[nb+64-t0+(j-i)]
        v2f wv = (e < 0) ? wold[16 + e] : wnew[e];
        acc[i] = __builtin_elementwise_fma(xv[j], wv, acc[i]);
      }
    }
  };

#pragma unroll 1
  for (int n0 = nstart; n0 < nend; n0 += NCHUNK) {
    // ---- stage w chunk [n0, n0+128) for 16 channels (pow2 indexing: shifts only) ----
    {
      const v2f* wsrc = w2pad + (size_t)cbase * KPAD + n0;
#pragma unroll
      for (int k = 0; k < 8; k++) {  // 16*128 = 2048 = 8*256
        int i = tid + k * 256;
        int c = i >> 7;
        int u = i & 127;
        wsh[c * WSTRIDE + u] = wsrc[(size_t)c * KPAD + u];
      }
    }
    __syncthreads();

    // ---- compute: one 16-n block per thread (same proven shape, half chunk) ----
    v2f wA[16], wB[16], xA[16];
#pragma unroll
    for (int m = 0; m < 16; m++) wA[m] = wrow[nbase + 48 - t0 + m];  // window before nbase
#pragma unroll
    for (int j = 0; j < 16; j++) xA[j] = xg[(size_t)(n0 + nbase + j) * C_];

    do16(nbase + 0, xA, wA, wB);
    __syncthreads();
  }

  // ---- reduce n-partials across np (2 rounds, half-size LDS), wave 0 atomic-adds fq ----
  v2f* fpart = wsh;  // reuse: [2][cl*65 + t], stride 65 (odd) -> conflict-free
  if (np >= 2) {
#pragma unroll
    for (int i = 0; i < 16; i++) fpart[(np - 2) * 1040 + cl * 65 + t0 + i] = acc[i];
  }
  __syncthreads();
  if (np < 2) {
#pragma unroll
    for (int i = 0; i < 16; i++) acc[i] += fpart[np * 1040 + cl * 65 + t0 + i];
  }
  __syncthreads();
  if (np == 1) {
#pragma unroll
    for (int i = 0; i < 16; i++) fpart[cl * 65 + t0 + i] = acc[i];
  }
  __syncthreads();
  if (np == 0) {
    float* op = (float*)(fq + (size_t)bb * 64 * C_ + cbase + cl);
#pragma unroll
    for (int i = 0; i < 16; i++) {
      v2f r = acc[i] + fpart[cl * 65 + t0 + i];
      size_t off = (size_t)(t0 + i) * C_ * 2;
      atomicAdd(op + off + 0, r.x);
      atomicAdd(op + off + 1, r.y);
    }
  }
}

// Apply per-channel 2x2 + cubic nonlinearity + shared 2x2, then the per-channel
// output filter over t. 64 blocks (b) x 256 threads (c x 2 t-halves).
__global__ void nonlin_out(const v2f* __restrict__ fq, const float* __restrict__ Anl,
                           const float* __restrict__ Wcm, const float* __restrict__ wor,
                           const float* __restrict__ woi, v2f* __restrict__ pre) {
  int b = blockIdx.x;
  int tid = threadIdx.x;
  int c = tid & 127, th = tid >> 7;
  float a00 = Anl[c * 4 + 0], a01 = Anl[c * 4 + 1];
  float a10 = Anl[c * 4 + 2], a11 = Anl[c * 4 + 3];
  float wc00 = Wcm[0], wc01 = Wcm[1], wc10 = Wcm[2], wc11 = Wcm[3];
  const v2f* f0 = fq + (size_t)b * 64 * C_ + c;
  float or_ = 0.f, oi_ = 0.f;
#pragma unroll 8
  for (int tt = 0; tt < 32; tt++) {
    int t = th * 32 + tt;
    v2f f = f0[(size_t)t * C_];
    float ur = a00 * f.x + a01 * f.y;
    float ui = a10 * f.x + a11 * f.y;
    float amp = ur * ur + ui * ui;
    ur *= amp;
    ui *= amp;
    float vr = wc00 * ur + wc01 * ui;
    float vi = wc10 * ur + wc11 * ui;
    or_ += vr * wor[c * 64 + t];
    oi_ += vi * woi[c * 64 + t];
  }
  __shared__ float redr[128], redi[128];
  if (th == 1) {
    redr[c] = or_;
    redi[c] = oi_;
  }
  __syncthreads();
  if (th == 0) {
    v2f r = {or_ + redr[c], oi_ + redi[c]};
    pre[(size_t)b * C_ + c] = r;
  }
}

// Train-mode BatchNorm1d over (B, comp) per channel. 128 blocks (c) x 128 threads.
__global__ void bn_kernel(const float* __restrict__ pre, const float* __restrict__ gamma,
                          const float* __restrict__ beta, float* __restrict__ out) {
  int c = blockIdx.x, tid = threadIdx.x;
  int b = tid >> 1, comp = tid & 1;
  float v = pre[((size_t)b * C_ + c) * 2 + comp];
  float s = v, s2 = v * v;
#pragma unroll
  for (int d = 32; d > 0; d >>= 1) {
    s += __shfl_down(s, d, 64);
    s2 += __shfl_down(s2, d, 64);
  }
  __shared__ float red[4];
  if ((tid & 63) == 0) {
    red[(tid >> 6) * 2 + 0] = s;
    red[(tid >> 6) * 2 + 1] = s2;
  }
  __syncthreads();
  float sum = red[0] + red[2], sumsq = red[1] + red[3];
  float mean = sum * 0.0078125f;
  float var = sumsq * 0.0078125f - mean * mean;
  float inv = rsqrtf(var + 1e-5f);
  out[((size_t)b * C_ + c) * 2 + comp] = (v - mean) * inv * gamma[c] + beta[c];
}

extern "C" void kernel_launch(void* const* d_in, const int* in_sizes, int n_in,
                              void* d_out, int out_size, void* d_ws, size_t ws_size,
                              hipStream_t stream) {
  (void)in_sizes; (void)n_in; (void)out_size; (void)ws_size;
  const float* x   = (const float*)d_in[0];
  const float* wir = (const float*)d_in[1];
  const float* wii = (const float*)d_in[2];
  const float* Anl = (const float*)d_in[3];
  const float* Wcm = (const float*)d_in[4];
  const float* wrr = (const float*)d_in[5];
  const float* wri = (const float*)d_in[6];
  const float* gam = (const float*)d_in[7];
  const float* bet = (const float*)d_in[8];

  v2f* w2pad = (v2f*)d_ws;  // 4.28 MB
  v2f* fq = (v2f*)((char*)d_ws + (size_t)C_ * KPAD * sizeof(v2f));  // 4.19 MB
  v2f* pre = (v2f*)((char*)fq + (size_t)B_ * 64 * C_ * sizeof(v2f));  // 64 KB

  prep_w<<<(C_ * KPAD) / 256, 256, 0, stream>>>(wir, wii, w2pad);
  zero_fq<<<1024, 256, 0, stream>>>((v4f*)fq);
  conv_main<<<B_ * 8 * NSPLIT, 256, 0, stream>>>((const v2f*)x, w2pad, fq);
  nonlin_out<<<B_, 256, 0, stream>>>(fq, Anl, Wcm, wrr, wri, pre);
  bn_kernel<<<C_, 128, 0, stream>>>((const float*)pre, gam, bet, (float*)d_out);
}

// Round 10
// 463.058 us; speedup vs baseline: 1.0507x; 1.0507x over previous
//
#include <hip/hip_runtime.h>

typedef float v2f __attribute__((ext_vector_type(2)));
typedef float v4f __attribute__((ext_vector_type(4)));

#define B_ 64
#define N_ 4096
#define C_ 128
#define W_ 64
#define WIN_ 4033
#define CG 16       // channels per block
#define NCHUNK 128  // n per staged chunk (r8-proven: best overhead/FMA ratio)
#define NSPLIT 4    // grid-level split of the n range (2048 blocks = 8/CU of work)
#define KPAD 4176   // padded w row: kk = k + 64, k in [-64, 4112)
#define WROW 192    // staged u range per chunk (NCHUNK + 64)
#define WSTRIDE 193 // LDS w row stride in float2 -- ODD so cl rows land on distinct bank pairs
#define PREPBLKS ((C_ * KPAD) / 256)  // 2088
#define ZEROBLKS ((B_ * 64 * C_) / 1024)  // 512 v2f -> 1024 blocks of 256 v4f... computed below

// Fused: build padded weight table AND zero the fq accumulator (saves one dispatch).
// Grid: 2088 prep blocks + 1024 zero blocks.
__global__ void prep_w(const float* __restrict__ wr, const float* __restrict__ wi,
                       v2f* __restrict__ w2pad, v4f* __restrict__ fqv) {
  int bid = blockIdx.x;
  if (bid >= PREPBLKS) {  // zero job: (64*64*128) v2f = 262144 v4f = 1024 blocks
    fqv[(size_t)(bid - PREPBLKS) * 256 + threadIdx.x] = (v4f){0.f, 0.f, 0.f, 0.f};
    return;
  }
  int idx = bid * 256 + threadIdx.x;  // exact: C_*KPAD = 2088*256
  int c = idx / KPAD;
  int kk = idx - c * KPAD;
  int k = kk - 64;
  v2f v = {0.f, 0.f};
  if (k >= 0 && k < WIN_) {
    v.x = wr[c * WIN_ + k];
    v.y = wi[c * WIN_ + k];
  }
  w2pad[idx] = v;
}

// Depthwise sliding correlation (both components packed), pre-nonlinearity partials.
// Grid: 64 b * 8 cgroups * NSPLIT = 2048 blocks, 256 threads, 25 KB LDS.
// OCCUPANCY-ARG EXPERIMENT (r9 post-mortem): across 10 rounds, waves/SIMD tracked the
// 2nd launch_bounds arg (2->1.7, 3->3.1 x4 rounds, 4->3.6, 6->3.9) while LDS (16.9-25KB)
// and grid (512-2048) changed nothing. VALU-busy is a measured constant ~182k cy/SIMD;
// conv time = 182k/utilization. This round: arg 3 -> 4 (VGPR cap 128; body's natural
// allocation is 64, measured x4). Spill cliff known at cap<=85 (r7); 128 untested here.
// Thread roles: cl = tid&15 (channel), t0g = (tid>>4)&3 (t-block), np = tid>>6 (32 n each).
__global__ __launch_bounds__(256, 4) void conv_main(
    const v2f* __restrict__ x2,     // [B][N][C] float2 (r,i)
    const v2f* __restrict__ w2pad,  // [C][KPAD]
    v2f* __restrict__ fq) {         // [B][64 t][C] accumulated via atomicAdd across ns
  __shared__ __attribute__((aligned(16))) v2f wsh[CG * WSTRIDE];  // 24.7 KB

  int tid = threadIdx.x;
  int bid = blockIdx.x;
  int cg = bid & 7;  // XCD-friendly: each XCD sees one w-slice (L2-resident, 535 KB)
  int bb = (bid >> 3) & 63;
  int ns = bid >> 9;
  int cbase = cg * CG;
  int cl = tid & 15;
  int t0 = ((tid >> 4) & 3) << 4;
  int np = tid >> 6;
  int nbase = np << 5;  // 32 n per wave-partition

  v2f zero = {0.f, 0.f};
  v2f acc[16];
#pragma unroll
  for (int i = 0; i < 16; i++) acc[i] = zero;

  const v2f* xg = x2 + (size_t)bb * N_ * C_ + cbase + cl;
  const v2f* wrow = wsh + cl * WSTRIDE;

  int nstart = ns * (N_ / NSPLIT);
  int nend = nstart + N_ / NSPLIT;  // 1024-n range -> 8 chunks

  // invariant: wold[m] = w2loc[nb+64-t0-16+m]; loads wnew[j] = w2loc[nb+64-t0+j]
  auto do16 = [&](int nb, const v2f* xv, const v2f* wold, v2f* wnew) {
#pragma unroll
    for (int j = 0; j < 16; j++) wnew[j] = wrow[nb + 64 - t0 + j];
#pragma unroll
    for (int j = 0; j < 16; j++) {
#pragma unroll
      for (int i = 0; i < 16; i++) {
        int e = j - i;  // need w2loc[nb+64-t0+(j-i)]
        v2f wv = (e < 0) ? wold[16 + e] : wnew[e];
        acc[i] = __builtin_elementwise_fma(xv[j], wv, acc[i]);
      }
    }
  };

#pragma unroll 1
  for (int n0 = nstart; n0 < nend; n0 += NCHUNK) {
    // ---- stage w chunk [n0, n0+192) for 16 channels ----
    {
      const v2f* wsrc = w2pad + (size_t)cbase * KPAD + n0;
#pragma unroll
      for (int k = 0; k < 12; k++) {  // 16*192 = 3072 = 12*256
        int i = tid + k * 256;
        int c = i / WROW;
        int u = i - c * WROW;
        wsh[c * WSTRIDE + u] = wsrc[(size_t)c * KPAD + u];
      }
    }
    __syncthreads();

    // ---- compute: self-contained chunk body (round-2/8 proven shape) ----
    v2f wA[16], wB[16], xA[16], xB[16];
#pragma unroll
    for (int m = 0; m < 16; m++) wA[m] = wrow[nbase + 48 - t0 + m];  // window before nbase
#pragma unroll
    for (int j = 0; j < 16; j++) xA[j] = xg[(size_t)(n0 + nbase + j) * C_];
#pragma unroll
    for (int j = 0; j < 16; j++) xB[j] = xg[(size_t)(n0 + nbase + 16 + j) * C_];

    do16(nbase + 0, xA, wA, wB);
    do16(nbase + 16, xB, wB, wA);
    __syncthreads();
  }

  // ---- reduce n-partials across np (2 rounds, half-size LDS), wave 0 atomic-adds fq ----
  v2f* fpart = wsh;  // reuse: [2][cl*65 + t], stride 65 (odd) -> conflict-free
  if (np >= 2) {
#pragma unroll
    for (int i = 0; i < 16; i++) fpart[(np - 2) * 1040 + cl * 65 + t0 + i] = acc[i];
  }
  __syncthreads();
  if (np < 2) {
#pragma unroll
    for (int i = 0; i < 16; i++) acc[i] += fpart[np * 1040 + cl * 65 + t0 + i];
  }
  __syncthreads();
  if (np == 1) {
#pragma unroll
    for (int i = 0; i < 16; i++) fpart[cl * 65 + t0 + i] = acc[i];
  }
  __syncthreads();
  if (np == 0) {
    float* op = (float*)(fq + (size_t)bb * 64 * C_ + cbase + cl);
#pragma unroll
    for (int i = 0; i < 16; i++) {
      v2f r = acc[i] + fpart[cl * 65 + t0 + i];
      size_t off = (size_t)(t0 + i) * C_ * 2;
      atomicAdd(op + off + 0, r.x);
      atomicAdd(op + off + 1, r.y);
    }
  }
}

// Apply per-channel 2x2 + cubic nonlinearity + shared 2x2, then the per-channel
// output filter over t. 64 blocks (b) x 256 threads (c x 2 t-halves).
__global__ void nonlin_out(const v2f* __restrict__ fq, const float* __restrict__ Anl,
                           const float* __restrict__ Wcm, const float* __restrict__ wor,
                           const float* __restrict__ woi, v2f* __restrict__ pre) {
  int b = blockIdx.x;
  int tid = threadIdx.x;
  int c = tid & 127, th = tid >> 7;
  float a00 = Anl[c * 4 + 0], a01 = Anl[c * 4 + 1];
  float a10 = Anl[c * 4 + 2], a11 = Anl[c * 4 + 3];
  float wc00 = Wcm[0], wc01 = Wcm[1], wc10 = Wcm[2], wc11 = Wcm[3];
  const v2f* f0 = fq + (size_t)b * 64 * C_ + c;
  float or_ = 0.f, oi_ = 0.f;
#pragma unroll 8
  for (int tt = 0; tt < 32; tt++) {
    int t = th * 32 + tt;
    v2f f = f0[(size_t)t * C_];
    float ur = a00 * f.x + a01 * f.y;
    float ui = a10 * f.x + a11 * f.y;
    float amp = ur * ur + ui * ui;
    ur *= amp;
    ui *= amp;
    float vr = wc00 * ur + wc01 * ui;
    float vi = wc10 * ur + wc11 * ui;
    or_ += vr * wor[c * 64 + t];
    oi_ += vi * woi[c * 64 + t];
  }
  __shared__ float redr[128], redi[128];
  if (th == 1) {
    redr[c] = or_;
    redi[c] = oi_;
  }
  __syncthreads();
  if (th == 0) {
    v2f r = {or_ + redr[c], oi_ + redi[c]};
    pre[(size_t)b * C_ + c] = r;
  }
}

// Train-mode BatchNorm1d over (B, comp) per channel. 128 blocks (c) x 128 threads.
__global__ void bn_kernel(const float* __restrict__ pre, const float* __restrict__ gamma,
                          const float* __restrict__ beta, float* __restrict__ out) {
  int c = blockIdx.x, tid = threadIdx.x;
  int b = tid >> 1, comp = tid & 1;
  float v = pre[((size_t)b * C_ + c) * 2 + comp];
  float s = v, s2 = v * v;
#pragma unroll
  for (int d = 32; d > 0; d >>= 1) {
    s += __shfl_down(s, d, 64);
    s2 += __shfl_down(s2, d, 64);
  }
  __shared__ float red[4];
  if ((tid & 63) == 0) {
    red[(tid >> 6) * 2 + 0] = s;
    red[(tid >> 6) * 2 + 1] = s2;
  }
  __syncthreads();
  float sum = red[0] + red[2], sumsq = red[1] + red[3];
  float mean = sum * 0.0078125f;
  float var = sumsq * 0.0078125f - mean * mean;
  float inv = rsqrtf(var + 1e-5f);
  out[((size_t)b * C_ + c) * 2 + comp] = (v - mean) * inv * gamma[c] + beta[c];
}

extern "C" void kernel_launch(void* const* d_in, const int* in_sizes, int n_in,
                              void* d_out, int out_size, void* d_ws, size_t ws_size,
                              hipStream_t stream) {
  (void)in_sizes; (void)n_in; (void)out_size; (void)ws_size;
  const float* x   = (const float*)d_in[0];
  const float* wir = (const float*)d_in[1];
  const float* wii = (const float*)d_in[2];
  const float* Anl = (const float*)d_in[3];
  const float* Wcm = (const float*)d_in[4];
  const float* wrr = (const float*)d_in[5];
  const float* wri = (const float*)d_in[6];
  const float* gam = (const float*)d_in[7];
  const float* bet = (const float*)d_in[8];

  v2f* w2pad = (v2f*)d_ws;  // 4.28 MB
  v2f* fq = (v2f*)((char*)d_ws + (size_t)C_ * KPAD * sizeof(v2f));  // 4.19 MB
  v2f* pre = (v2f*)((char*)fq + (size_t)B_ * 64 * C_ * sizeof(v2f));  // 64 KB

  prep_w<<<PREPBLKS + 1024, 256, 0, stream>>>(wir, wii, w2pad, (v4f*)fq);
  conv_main<<<B_ * 8 * NSPLIT, 256, 0, stream>>>((const v2f*)x, w2pad, fq);
  nonlin_out<<<B_, 256, 0, stream>>>(fq, Anl, Wcm, wrr, wri, pre);
  bn_kernel<<<C_, 128, 0, stream>>>((const float*)pre, gam, bet, (float*)d_out);
}